// Round 3
// baseline (564.354 us; speedup 1.0000x reference)
//
#include <hip/hip_runtime.h>
#include <hip/hip_fp16.h>

// WindowAttention fused kernel for MI355X (gfx950).
// B=4096 windows, N=49 tokens (pad 64), C=192, H=6, hd=32.
// V4: head-PAIR interleaved attention loop (two independent dependency
// chains per wave -> MFMA/bpermute/softmax latency of head A hides under
// head B). exp2-domain softmax (Q pre-scaled by scale*log2e, bmT baked with
// log2e) and tree reductions shorten the serial chain. Structure otherwise
// = V3: all-heads QKV once (x in regs/AGPRs), Q/K/V^T all heads in LDS,
// 3 barriers/block total.

typedef short bf16x8 __attribute__((ext_vector_type(8)));
typedef float f32x4 __attribute__((ext_vector_type(4)));

#define MFMA16(a, b, c) __builtin_amdgcn_mfma_f32_16x16x32_bf16((a), (b), (c), 0, 0, 0)

#define DIMC 192
#define NTOK 49

// round-to-nearest-even fp32 -> bf16
__device__ __forceinline__ unsigned short f2bf(float f) {
  unsigned int u = __float_as_uint(f);
  u += 0x7fffu + ((u >> 16) & 1u);
  return (unsigned short)(u >> 16);
}

// packed fp32x2 -> bf16x2 (RNE), single VALU op
__device__ __forceinline__ unsigned int cvt_pk_bf16(float lo, float hi) {
  unsigned int r;
  asm("v_cvt_pk_bf16_f32 %0, %1, %2" : "=v"(r) : "v"(lo), "v"(hi));
  return r;
}

// prep: bf16 weights + combined (bias+mask)*log2e fp16 table, frag-permuted:
// bm[widx][h] tile of 4096 halfs, offset = ((nt*4 + lq)*64 + q)*4 + r,
// value = (bias[h][q][k] + mask[widx][q][k]) * log2e, k = nt*16 + lq*4 + r.
// k >= 49 -> -43281 (= -30000*log2e), q >= 49 -> 0 (rows discarded).
__global__ void prep_kernel(const float* __restrict__ qkv_w,
                            const float* __restrict__ proj_w,
                            const float* __restrict__ bias_table,
                            const int* __restrict__ rel_idx,
                            const float* __restrict__ mask,
                            unsigned short* __restrict__ qkv_wb,
                            unsigned short* __restrict__ proj_wb,
                            __half* __restrict__ bmT) {
  const float LOG2E = 1.4426950408889634f;
  int i = blockIdx.x * 256 + threadIdx.x;
  if (i < 576 * 192) qkv_wb[i] = f2bf(qkv_w[i]);
  if (i < 192 * 192) proj_wb[i] = f2bf(proj_w[i]);
  {
    int r = i & 3;
    int q = (i >> 2) & 63;
    int lq = (i >> 8) & 3;
    int nt = (i >> 10) & 3;
    int hw = i >> 12;          // widx*6 + h
    int h = hw % 6;
    int widx = hw / 6;
    int k = nt * 16 + lq * 4 + r;
    float v;
    if (k >= NTOK) v = -30000.f * LOG2E;
    else if (q >= NTOK) v = 0.f;
    else v = (bias_table[rel_idx[q * NTOK + k] * 6 + h] +
              mask[(size_t)widx * (NTOK * NTOK) + q * NTOK + k]) * LOG2E;
    bmT[i] = __float2half(v);
  }
}

__global__ __launch_bounds__(256, 2) void winattn_kernel(
    const float* __restrict__ x,
    const float* __restrict__ qkv_b,
    const float* __restrict__ proj_b,
    const unsigned short* __restrict__ qkv_wb,
    const unsigned short* __restrict__ proj_wb,
    const __half* __restrict__ bmT,
    float* __restrict__ out) {
  // LDS pool: 78,848 B -> 2 blocks/CU. xb (transient) aliases Qall.
  __shared__ unsigned short pool[39424];
  unsigned short* xb   = pool;            // [64][200] bf16 x, dead after reg-load
  unsigned short* Qall = pool;            // [64 tok][200] scaled Q (cols 0..191)
  unsigned short* Kall = pool + 12800;    // [64 tok][200]
  unsigned short* Vta  = pool + 25600;    // [192 d][72 tok]  (V^T, all heads)

  const int tid = threadIdx.x;
  const int b = blockIdx.x;
  const int widx = b & 63;
  const int lane = tid & 63;
  const int wv = tid >> 6;          // wave 0..3
  const int lq = lane >> 4;         // quad 0..3
  const int ln = lane & 15;

  // ---------------- stage x (bf16, zero rows >= 49)
  {
    const float4* xp = (const float4*)(x + (size_t)b * (NTOK * DIMC));
    for (int i = tid; i < NTOK * DIMC / 4; i += 256) {
      float4 v = xp[i];
      int fl = i * 4;
      int r = fl / DIMC;
      int c = fl - r * DIMC;
      unsigned int lo = (unsigned int)f2bf(v.x) | ((unsigned int)f2bf(v.y) << 16);
      unsigned int hi = (unsigned int)f2bf(v.z) | ((unsigned int)f2bf(v.w) << 16);
      *(uint2*)(&xb[r * 200 + c]) = make_uint2(lo, hi);
    }
    for (int i = tid; i < 15 * 200 / 2; i += 256)
      ((unsigned int*)(&xb[49 * 200]))[i] = 0u;
  }
  __syncthreads();

  // ---------------- hoist all of x into registers as MFMA A-frags.
  // af[mt][ks]: rows mt*16+ln, k = ks*32 + lq*8 .. +7
  bf16x8 af[4][6];
#pragma unroll
  for (int mt = 0; mt < 4; ++mt)
#pragma unroll
    for (int ks = 0; ks < 6; ++ks)
      af[mt][ks] = *(const bf16x8*)&xb[(mt * 16 + ln) * 200 + ks * 32 + lq * 8];
  __syncthreads();  // xb dead; its LDS becomes Qall

  // scale * log2e: softmax runs in exp2 domain (exact same softmax)
  const float scale2 = 0.17677669529663687f * 1.4426950408889634f;

  // ---------------- QKV for ALL heads: 36 col-tiles, wave owns 9 complete
  // columns (all 4 m-tiles each) -> every weight fetched once per block.
  for (int i = 0; i < 9; ++i) {
    int nt = wv * 9 + i;
    int c = nt * 16 + ln;                         // global out col 0..575
    const unsigned short* wp = qkv_wb + (size_t)c * DIMC + lq * 8;
    bf16x8 wf[6];
#pragma unroll
    for (int ks = 0; ks < 6; ++ks) wf[ks] = *(const bf16x8*)(wp + ks * 32);
    float bv = qkv_b[c];
    f32x4 a0 = (f32x4){bv, bv, bv, bv};
    f32x4 a1 = a0, a2 = a0, a3 = a0;
#pragma unroll
    for (int ks = 0; ks < 6; ++ks) {
      a0 = MFMA16(af[0][ks], wf[ks], a0);
      a1 = MFMA16(af[1][ks], wf[ks], a1);
      a2 = MFMA16(af[2][ks], wf[ks], a2);
      a3 = MFMA16(af[3][ks], wf[ks], a3);
    }
    f32x4 acc[4] = {a0, a1, a2, a3};
    // C-layout: row(token) = mt*16 + lq*4 + r, col = c (lane ln)
    int which = nt / 12;                          // 0=Q 1=K 2=V (tile-uniform)
    int colq = c - which * 192;                   // col within 192
    if (which == 0) {
#pragma unroll
      for (int mt = 0; mt < 4; ++mt) {
        int row0 = mt * 16 + lq * 4;
#pragma unroll
        for (int r = 0; r < 4; ++r)
          Qall[(row0 + r) * 200 + colq] = f2bf(acc[mt][r] * scale2);
      }
    } else if (which == 1) {
#pragma unroll
      for (int mt = 0; mt < 4; ++mt) {
        int row0 = mt * 16 + lq * 4;
#pragma unroll
        for (int r = 0; r < 4; ++r)
          Kall[(row0 + r) * 200 + colq] = f2bf(acc[mt][r]);
      }
    } else {
#pragma unroll
      for (int mt = 0; mt < 4; ++mt) {
        int row0 = mt * 16 + lq * 4;
        unsigned int lo = cvt_pk_bf16(acc[mt][0], acc[mt][1]);
        unsigned int hi = cvt_pk_bf16(acc[mt][2], acc[mt][3]);
        *(uint2*)(&Vta[colq * 72 + row0]) = make_uint2(lo, hi);
      }
    }
  }
  __syncthreads();  // Q/K/V^T (all heads) ready; NO more barriers below.

  // persistent proj accumulators: wave owns q-rows [wv*16, wv*16+16), all 192 cols
  f32x4 pacc[12];
#pragma unroll
  for (int nti = 0; nti < 12; ++nti) {
    float pbv = proj_b[nti * 16 + ln];
    pacc[nti] = (f32x4){pbv, pbv, pbv, pbv};
  }

  const __half* bmp = bmT + (size_t)widx * 6 * 4096;
  // cross-lq redistribution source lanes (same ln, lq_s = (lq&1)*2 + {0,1})
  const int sA = ((lq & 1) << 5) | ln;
  const int sB = sA + 16;
  const int hiSel = lq >> 1;
  union U8 { unsigned int u[4]; bf16x8 v; };

  // ---------------- head-PAIR loop: two independent chains per iteration
  for (int hp = 0; hp < 3; ++hp) {
    const int h0 = hp * 2;

    // bias+mask fragments for both heads (issued first, hidden under MFMAs)
    uint2 bmu[2][4];
#pragma unroll
    for (int j = 0; j < 2; ++j) {
      const __half* bmh = bmp + (size_t)(h0 + j) * 4096;
#pragma unroll
      for (int nt = 0; nt < 4; ++nt)
        bmu[j][nt] = *(const uint2*)(bmh + ((nt * 4 + lq) * 64 + wv * 16 + ln) * 4);
    }

    // S^T = K Q^T for both heads
    bf16x8 qf[2];
#pragma unroll
    for (int j = 0; j < 2; ++j)
      qf[j] = *(const bf16x8*)&Qall[(wv * 16 + ln) * 200 + (h0 + j) * 32 + lq * 8];
    f32x4 sv[2][4];
#pragma unroll
    for (int nt = 0; nt < 4; ++nt)
#pragma unroll
      for (int j = 0; j < 2; ++j) {
        bf16x8 kf = *(const bf16x8*)&Kall[(nt * 16 + ln) * 200 + (h0 + j) * 32 + lq * 8];
        sv[j][nt] = MFMA16(kf, qf[j], ((f32x4){0.f, 0.f, 0.f, 0.f}));
      }

    // bias+mask add (already in exp2 domain)
    float tt[2][4][4];
#pragma unroll
    for (int j = 0; j < 2; ++j)
#pragma unroll
      for (int nt = 0; nt < 4; ++nt) {
        float2 f01 = __half22float2(*(const __half2*)&bmu[j][nt].x);
        float2 f23 = __half22float2(*(const __half2*)&bmu[j][nt].y);
        tt[j][nt][0] = sv[j][nt][0] + f01.x;
        tt[j][nt][1] = sv[j][nt][1] + f01.y;
        tt[j][nt][2] = sv[j][nt][2] + f23.x;
        tt[j][nt][3] = sv[j][nt][3] + f23.y;
      }

    // softmax over k (exp2 domain): tree max, exp2, tree sum; lq-reduce
    float pinv[2];
#pragma unroll
    for (int j = 0; j < 2; ++j) {
      float m0 = fmaxf(fmaxf(tt[j][0][0], tt[j][0][1]), fmaxf(tt[j][0][2], tt[j][0][3]));
      float m1 = fmaxf(fmaxf(tt[j][1][0], tt[j][1][1]), fmaxf(tt[j][1][2], tt[j][1][3]));
      float m2 = fmaxf(fmaxf(tt[j][2][0], tt[j][2][1]), fmaxf(tt[j][2][2], tt[j][2][3]));
      float m3 = fmaxf(fmaxf(tt[j][3][0], tt[j][3][1]), fmaxf(tt[j][3][2], tt[j][3][3]));
      float m = fmaxf(fmaxf(m0, m1), fmaxf(m2, m3));
      m = fmaxf(m, __shfl_xor(m, 16, 64));
      m = fmaxf(m, __shfl_xor(m, 32, 64));
      float s[4];
#pragma unroll
      for (int nt = 0; nt < 4; ++nt) {
        float e0 = exp2f(tt[j][nt][0] - m);
        float e1 = exp2f(tt[j][nt][1] - m);
        float e2 = exp2f(tt[j][nt][2] - m);
        float e3 = exp2f(tt[j][nt][3] - m);
        tt[j][nt][0] = e0; tt[j][nt][1] = e1;
        tt[j][nt][2] = e2; tt[j][nt][3] = e3;
        s[nt] = (e0 + e1) + (e2 + e3);
      }
      float sum = (s[0] + s[1]) + (s[2] + s[3]);
      sum += __shfl_xor(sum, 16, 64);
      sum += __shfl_xor(sum, 32, 64);
      pinv[j] = 1.f / sum;
    }

    // pack P^T to bf16 pairs
    unsigned int pk[2][4][2];
#pragma unroll
    for (int j = 0; j < 2; ++j)
#pragma unroll
      for (int nt = 0; nt < 4; ++nt) {
        pk[j][nt][0] = cvt_pk_bf16(tt[j][nt][0], tt[j][nt][1]);
        pk[j][nt][1] = cvt_pk_bf16(tt[j][nt][2], tt[j][nt][3]);
      }

    // redistribute to PV B-frag words (cross-lq shuffle)
    U8 pb0[2], pb1[2];
#pragma unroll
    for (int w = 0; w < 4; ++w) {
      int src = (w & 2) ? sB : sA;
#pragma unroll
      for (int j = 0; j < 2; ++j) {
        int a0 = __shfl((int)pk[j][0][w & 1], src, 64);
        int a1 = __shfl((int)pk[j][1][w & 1], src, 64);
        int b0 = __shfl((int)pk[j][2][w & 1], src, 64);
        int b1 = __shfl((int)pk[j][3][w & 1], src, 64);
        pb0[j].u[w] = (unsigned int)(hiSel ? a1 : a0);
        pb1[j].u[w] = (unsigned int)(hiSel ? b1 : b0);
      }
    }

    // O^T = V^T P^T for both heads
    f32x4 o[2][2];
#pragma unroll
    for (int db = 0; db < 2; ++db)
#pragma unroll
      for (int j = 0; j < 2; ++j) {
        bf16x8 v0 = *(const bf16x8*)&Vta[((h0 + j) * 32 + db * 16 + ln) * 72 + lq * 8];
        bf16x8 v1 = *(const bf16x8*)&Vta[((h0 + j) * 32 + db * 16 + ln) * 72 + 32 + lq * 8];
        f32x4 acc = (f32x4){0.f, 0.f, 0.f, 0.f};
        acc = MFMA16(v0, pb0[j].v, acc);
        acc = MFMA16(v1, pb1[j].v, acc);
        o[j][db] = acc;
      }

    // normalize + pack O^T, redistribute to proj A-frag
    unsigned int pkO[2][2][2];
#pragma unroll
    for (int j = 0; j < 2; ++j)
#pragma unroll
      for (int db = 0; db < 2; ++db) {
        pkO[j][db][0] = cvt_pk_bf16(o[j][db][0] * pinv[j], o[j][db][1] * pinv[j]);
        pkO[j][db][1] = cvt_pk_bf16(o[j][db][2] * pinv[j], o[j][db][3] * pinv[j]);
      }
    U8 oa[2];
#pragma unroll
    for (int w = 0; w < 4; ++w) {
      int src = (w & 2) ? sB : sA;
#pragma unroll
      for (int j = 0; j < 2; ++j) {
        int a0 = __shfl((int)pkO[j][0][w & 1], src, 64);
        int a1 = __shfl((int)pkO[j][1][w & 1], src, 64);
        oa[j].u[w] = (unsigned int)(hiSel ? a1 : a0);
      }
    }

    // partial proj for both heads: A = O rows (q = wv*16+ln, d = lq*8..+7)
#pragma unroll
    for (int nti = 0; nti < 12; ++nti) {
#pragma unroll
      for (int j = 0; j < 2; ++j) {
        bf16x8 w = *(const bf16x8*)(proj_wb +
            (size_t)(nti * 16 + ln) * DIMC + (h0 + j) * 32 + lq * 8);
        pacc[nti] = MFMA16(oa[j].v, w, pacc[nti]);
      }
    }
  }

  // ---------------- store output (fp32): wave's q-rows, all 192 cols
  {
    float* outp = out + (size_t)b * (NTOK * DIMC);
#pragma unroll
    for (int nti = 0; nti < 12; ++nti) {
      int col = nti * 16 + ln;
#pragma unroll
      for (int r = 0; r < 4; ++r) {
        int row = wv * 16 + lq * 4 + r;
        if (row < NTOK) outp[row * DIMC + col] = pacc[nti][r];
      }
    }
  }
}

extern "C" void kernel_launch(void* const* d_in, const int* in_sizes, int n_in,
                              void* d_out, int out_size, void* d_ws, size_t ws_size,
                              hipStream_t stream) {
  const float* x = (const float*)d_in[0];
  const float* mask = (const float*)d_in[1];
  const float* qkv_w = (const float*)d_in[2];
  const float* qkv_b = (const float*)d_in[3];
  const float* proj_w = (const float*)d_in[4];
  const float* proj_b = (const float*)d_in[5];
  const float* bias_table = (const float*)d_in[6];
  const int* rel_idx = (const int*)d_in[7];

  unsigned short* qkv_wb = (unsigned short*)d_ws;                 // 576*192 bf16
  unsigned short* proj_wb = qkv_wb + 576 * 192;                   // 192*192 bf16
  __half* bmT = (__half*)(proj_wb + 192 * 192);                   // 64*6*4096 fp16

  prep_kernel<<<6144, 256, 0, stream>>>(qkv_w, proj_w, bias_table, rel_idx,
                                        mask, qkv_wb, proj_wb, bmT);
  winattn_kernel<<<4096, 256, 0, stream>>>(x, qkv_b, proj_b,
                                           qkv_wb, proj_wb, bmT,
                                           (float*)d_out);
}